// Round 1
// baseline (10564.339 us; speedup 1.0000x reference)
//
#include <hip/hip_runtime.h>
#include <stdint.h>

#define T_ 1024
#define H_ 256
#define G_ 768

typedef __attribute__((ext_vector_type(8))) short bf16x8;
typedef __attribute__((ext_vector_type(4))) float f32x4;

__device__ __forceinline__ unsigned short f2bf(float f) {
    union { float f; uint32_t u; } v; v.f = f;
    uint32_t u = v.u;
    return (unsigned short)((u + 0x7FFFu + ((u >> 16) & 1u)) >> 16);
}

__device__ __forceinline__ float sigm(float x) {
    x = fminf(fmaxf(x, -30.f), 30.f);
    return 1.f / (1.f + __expf(-x));
}
__device__ __forceinline__ float tanh_f(float x) {
    x = fminf(fmaxf(x, -15.f), 15.f);
    float e = __expf(2.f * x);
    return (e - 1.f) / (e + 1.f);
}

__device__ __forceinline__ void gload_lds16(const void* g, void* l) {
    __builtin_amdgcn_global_load_lds((const __attribute__((address_space(1))) void*)g,
                                     (__attribute__((address_space(3))) void*)l,
                                     16, 0, 0);
}

// Pack W (f32 [layer][768][256]) into per-wave MFMA A-fragment order:
// flat = ((((layer*8 + w)*6 + mt)*8 + kt)*64 + l)*8 + j
// gate = (mt>>1)*256 + w*32 + (mt&1)*16 + (l&15)
// k    = kt*32 + (j&3) + ((l>>4)<<2) + ((j>>2)<<4)
__global__ void pack_weights(const float* __restrict__ W_ih, const float* __restrict__ W_hh,
                             unsigned short* __restrict__ pIH, unsigned short* __restrict__ pHH)
{
    int idx = blockIdx.x * blockDim.x + threadIdx.x;
    if (idx >= 2 * 8 * 6 * 8 * 64 * 8) return;
    int pos = idx;
    int j = pos & 7;  pos >>= 3;
    int l = pos & 63; pos >>= 6;
    int kt = pos & 7; pos >>= 3;
    int mt = pos % 6; pos /= 6;
    int w = pos & 7;  pos >>= 3;
    int layer = pos;
    int gate = (mt >> 1) * 256 + w * 32 + (mt & 1) * 16 + (l & 15);
    int k = kt * 32 + (j & 3) + ((l >> 4) << 2) + ((j >> 2) << 4);
    size_t src = (size_t)layer * G_ * H_ + (size_t)gate * H_ + k;
    pIH[idx] = f2bf(W_ih[src]);
    pHH[idx] = f2bf(W_hh[src]);
}

// xg GEMM: xg^T-tiles = W_ih . seq^T, output in C-fragment layout:
// xg[toff][bblk][w][mt][lane][4] f32
// Layer0 src: x f32 [B][T][H]; Layer1 src: hseq bf16 [bblk][t][k][b] (neutral image)
template<bool SRC_BF16>
__global__ __launch_bounds__(512, 2)
void gemm_xg(const void* __restrict__ srcp, const unsigned short* __restrict__ wpack,
             float* __restrict__ xg, int t0)
{
    extern __shared__ char smem[];
    unsigned short* Bt = (unsigned short*)smem; // [8][256][16] bf16 = 64KB
    const int tid = threadIdx.x;
    const int w = tid >> 6, l = tid & 63;
    const int bblk = blockIdx.x & 7;
    const int tg = blockIdx.x >> 3;
    const int tbase = t0 + tg * 8;
    const int b = l & 15, g = l >> 4;

    bf16x8 af[6][8];
    {
        const bf16x8* wp = (const bf16x8*)wpack;
        #pragma unroll
        for (int mt = 0; mt < 6; ++mt)
            #pragma unroll
            for (int kt = 0; kt < 8; ++kt)
                af[mt][kt] = wp[((w * 6 + mt) * 8 + kt) * 64 + l];
    }

    if (!SRC_BF16) {
        const float* x = (const float*)srcp;
        const int t_i = w;                 // wave w stages time-slot w
        const int sb = (l >> 2) & 15;      // batch row within block
        const int f0 = (l & 3) * 64;       // feature segment
        const float* row = x + ((size_t)(bblk * 16 + sb) * T_ + (tbase + t_i)) * H_ + f0;
        unsigned short* bt = Bt + t_i * 4096;
        #pragma unroll
        for (int i = 0; i < 64; i += 4) {
            f32x4 v = *(const f32x4*)(row + i);
            int f = f0 + i;
            bt[(f + 0) * 16 + sb] = f2bf(v[0]);
            bt[(f + 1) * 16 + sb] = f2bf(v[1]);
            bt[(f + 2) * 16 + sb] = f2bf(v[2]);
            bt[(f + 3) * 16 + sb] = f2bf(v[3]);
        }
    } else {
        const unsigned short* hs = (const unsigned short*)srcp;
        #pragma unroll
        for (int t_i = 0; t_i < 8; ++t_i) {
            const unsigned short* src = hs + ((size_t)bblk * T_ + (tbase + t_i)) * 4096
                                           + w * 512 + l * 8;
            gload_lds16(src, Bt + t_i * 4096 + w * 512);
        }
    }
    __syncthreads();

    #pragma unroll 1
    for (int t_i = 0; t_i < 8; ++t_i) {
        const unsigned short* bt = Bt + t_i * 4096;
        f32x4 acc[6];
        #pragma unroll
        for (int mt = 0; mt < 6; ++mt) acc[mt] = (f32x4){0.f, 0.f, 0.f, 0.f};
        #pragma unroll
        for (int kt = 0; kt < 8; ++kt) {
            bf16x8 bf;
            #pragma unroll
            for (int j = 0; j < 8; ++j) {
                int k = kt * 32 + (j & 3) + (g << 2) + ((j >> 2) << 4);
                bf[j] = (short)bt[k * 16 + b];
            }
            #pragma unroll
            for (int mt = 0; mt < 6; ++mt)
                acc[mt] = __builtin_amdgcn_mfma_f32_16x16x32_bf16(af[mt][kt], bf, acc[mt], 0, 0, 0);
        }
        f32x4* dst = (f32x4*)xg + (((size_t)(tg * 8 + t_i) * 8 + bblk) * 8 + w) * 6 * 64;
        #pragma unroll
        for (int mt = 0; mt < 6; ++mt)
            dst[mt * 64 + l] = acc[mt];
    }
}

// Persistent recurrence: 8 blocks x 16 batch rows, W_hh resident in VGPRs.
template<int LAYER>
__global__ __launch_bounds__(512, 2)
void recur(const float* __restrict__ xg, const unsigned short* __restrict__ wpack,
           const float* __restrict__ bih, const float* __restrict__ bhh,
           unsigned short* __restrict__ hseq, float* __restrict__ hstate,
           float* __restrict__ h2last, int t0, int nsteps, int first)
{
    extern __shared__ char smem[];
    float* xgbuff = (float*)smem;                             // [2][8][6][64][4] f32 = 98304 B
    unsigned short* hbuf = (unsigned short*)(smem + 98304);   // [2][256][16] bf16 = 16384 B
    float* biasl = (float*)(smem + 98304 + 16384);            // [1024] f32
    (void)xgbuff;
    const int tid = threadIdx.x;
    const int w = tid >> 6, l = tid & 63;
    const int bblk = blockIdx.x;
    const int b = l & 15, g = l >> 4;

    bf16x8 af[6][8];
    {
        const bf16x8* wp = (const bf16x8*)wpack;
        #pragma unroll
        for (int mt = 0; mt < 6; ++mt)
            #pragma unroll
            for (int kt = 0; kt < 8; ++kt)
                af[mt][kt] = wp[((w * 6 + mt) * 8 + kt) * 64 + l];
    }

    biasl[tid] = bih[tid] + bhh[tid];          // r,z summed biases (gates 0..511)
    if (tid < 256) {
        biasl[512 + tid] = bih[512 + tid];     // b_ih_n
        biasl[768 + tid] = bhh[512 + tid];     // b_hh_n
    }

    float hreg[2][4];
    if (first) {
        #pragma unroll
        for (int s = 0; s < 2; ++s)
            #pragma unroll
            for (int q = 0; q < 4; ++q) hreg[s][q] = 0.f;
    } else {
        const f32x4* hsv = (const f32x4*)hstate + ((size_t)(bblk * 8 + w) * 64 + l) * 2;
        f32x4 a0 = hsv[0], a1 = hsv[1];
        hreg[0][0] = a0[0]; hreg[0][1] = a0[1]; hreg[0][2] = a0[2]; hreg[0][3] = a0[3];
        hreg[1][0] = a1[0]; hreg[1][1] = a1[1]; hreg[1][2] = a1[2]; hreg[1][3] = a1[3];
    }
    #pragma unroll
    for (int s = 0; s < 2; ++s)
        #pragma unroll
        for (int q = 0; q < 4; ++q) {
            int k = w * 32 + s * 16 + (g << 2) + q;
            hbuf[k * 16 + b] = f2bf(hreg[s][q]);
        }

    // prologue: prefetch xg for it=0 into parity 0
    {
        const float* sbase = xg + (((size_t)0 * 8 + bblk) * 8 + w) * 6 * 256;
        #pragma unroll
        for (int mt = 0; mt < 6; ++mt)
            gload_lds16(sbase + mt * 256 + l * 4, smem + (w * 6 + mt) * 1024);
    }
    __syncthreads();

    #pragma unroll 1
    for (int it = 0; it < nsteps; ++it) {
        const int p = it & 1;
        if (it + 1 < nsteps) {
            const float* sbase = xg + (((size_t)(it + 1) * 8 + bblk) * 8 + w) * 6 * 256;
            char* dbase = smem + (p ^ 1) * 49152;
            #pragma unroll
            for (int mt = 0; mt < 6; ++mt)
                gload_lds16(sbase + mt * 256 + l * 4, dbase + (w * 6 + mt) * 1024);
        }
        // hg^T = W_hh . h^T
        const unsigned short* hb = hbuf + p * 4096;
        f32x4 acc[6];
        #pragma unroll
        for (int mt = 0; mt < 6; ++mt) acc[mt] = (f32x4){0.f, 0.f, 0.f, 0.f};
        #pragma unroll
        for (int kt = 0; kt < 8; ++kt) {
            bf16x8 bf;
            #pragma unroll
            for (int j = 0; j < 8; ++j) {
                int k = kt * 32 + (j & 3) + (g << 2) + ((j >> 2) << 4);
                bf[j] = (short)hb[k * 16 + b];
            }
            #pragma unroll
            for (int mt = 0; mt < 6; ++mt)
                acc[mt] = __builtin_amdgcn_mfma_f32_16x16x32_bf16(af[mt][kt], bf, acc[mt], 0, 0, 0);
        }
        // gates (xg prefetched last iter; end-of-iter barrier drained vmcnt)
        const f32x4* xv = (const f32x4*)(smem + p * 49152) + w * 6 * 64;
        #pragma unroll
        for (int s = 0; s < 2; ++s) {
            f32x4 xr = xv[(0 + s) * 64 + l];
            f32x4 xz = xv[(2 + s) * 64 + l];
            f32x4 xn = xv[(4 + s) * 64 + l];
            #pragma unroll
            for (int q = 0; q < 4; ++q) {
                int go = w * 32 + s * 16 + (g << 2) + q;   // hidden index
                float r = sigm(xr[q] + acc[0 + s][q] + biasl[go]);
                float z = sigm(xz[q] + acc[2 + s][q] + biasl[256 + go]);
                float n = tanh_f(xn[q] + biasl[512 + go] + r * (acc[4 + s][q] + biasl[768 + go]));
                float hn = n + z * (hreg[s][q] - n);
                hreg[s][q] = hn;
                hbuf[(p ^ 1) * 4096 + go * 16 + b] = f2bf(hn);
            }
        }
        __syncthreads();
        if (LAYER == 0) {
            const int4* sv = (const int4*)(hbuf + (p ^ 1) * 4096 + w * 512 + l * 8);
            int4* dv = (int4*)(hseq + ((size_t)bblk * T_ + (t0 + it)) * 4096 + w * 512 + l * 8);
            *dv = *sv;
        }
    }

    f32x4* hsv = (f32x4*)hstate + ((size_t)(bblk * 8 + w) * 64 + l) * 2;
    hsv[0] = (f32x4){hreg[0][0], hreg[0][1], hreg[0][2], hreg[0][3]};
    hsv[1] = (f32x4){hreg[1][0], hreg[1][1], hreg[1][2], hreg[1][3]};
    if (LAYER == 1 && t0 + nsteps == T_) {
        #pragma unroll
        for (int s = 0; s < 2; ++s)
            #pragma unroll
            for (int q = 0; q < 4; ++q) {
                int k = w * 32 + s * 16 + (g << 2) + q;
                h2last[(size_t)(bblk * 16 + b) * H_ + k] = hreg[s][q];
            }
    }
}

__global__ void fc_out(const float* __restrict__ h2, const float* __restrict__ W_fc,
                       const float* __restrict__ b_fc, float* __restrict__ out)
{
    __shared__ float hrow[256];
    const int bb = blockIdx.x, i = threadIdx.x;
    hrow[i] = h2[(size_t)bb * 256 + i];
    __syncthreads();
    float acc = b_fc[i];
    const float* wr = W_fc + (size_t)i * 256;
    #pragma unroll 8
    for (int k = 0; k < 256; ++k) acc += hrow[k] * wr[k];
    out[(size_t)bb * 256 + i] = sigm(acc);
}

extern "C" void kernel_launch(void* const* d_in, const int* in_sizes, int n_in,
                              void* d_out, int out_size, void* d_ws, size_t ws_size,
                              hipStream_t stream)
{
    const float* x    = (const float*)d_in[0];
    const float* W_ih = (const float*)d_in[1];
    const float* W_hh = (const float*)d_in[2];
    const float* b_ih = (const float*)d_in[3];
    const float* b_hh = (const float*)d_in[4];
    const float* W_fc = (const float*)d_in[5];
    const float* b_fc = (const float*)d_in[6];
    float* out = (float*)d_out;

    const size_t HSEQ_B = (size_t)8 * T_ * 4096 * 2;   // 64 MB
    const size_t PACK_B = 393216ull * 2;               // 768 KB each
    const size_t HST_B = 131072, H2_B = 131072;
    size_t fixed = HSEQ_B + 2 * PACK_B + HST_B + H2_B;
    int chunk = 1024;
    while (chunk > 64 && fixed + (size_t)chunk * 98304 * 4 > ws_size) chunk >>= 1;

    char* ws = (char*)d_ws;
    float* xg = (float*)ws;
    size_t off = (size_t)chunk * 98304 * 4;
    unsigned short* hseq = (unsigned short*)(ws + off); off += HSEQ_B;
    unsigned short* pIH  = (unsigned short*)(ws + off); off += PACK_B;
    unsigned short* pHH  = (unsigned short*)(ws + off); off += PACK_B;
    float* hstate = (float*)(ws + off); off += HST_B;
    float* h2     = (float*)(ws + off);

    pack_weights<<<1536, 256, 0, stream>>>(W_ih, W_hh, pIH, pHH);

    const int RLDS = 98304 + 16384 + 4096;
    for (int layer = 0; layer < 2; ++layer) {
        const unsigned short* wIH = pIH + (size_t)layer * 196608;
        const unsigned short* wHH = pHH + (size_t)layer * 196608;
        const float* bi = b_ih + layer * G_;
        const float* bh = b_hh + layer * G_;
        for (int c = 0; c * chunk < T_; ++c) {
            int t0 = c * chunk;
            if (layer == 0) {
                gemm_xg<false><<<chunk, 512, 65536, stream>>>(x, wIH, xg, t0);
                recur<0><<<8, 512, RLDS, stream>>>(xg, wHH, bi, bh, hseq, hstate, h2,
                                                   t0, chunk, c == 0);
            } else {
                gemm_xg<true><<<chunk, 512, 65536, stream>>>(hseq, wIH, xg, t0);
                recur<1><<<8, 512, RLDS, stream>>>(xg, wHH, bi, bh, hseq, hstate, h2,
                                                   t0, chunk, c == 0);
            }
        }
    }
    fc_out<<<128, 256, 0, stream>>>(h2, W_fc, b_fc, out);
}

// Round 2
// 5971.029 us; speedup vs baseline: 1.7693x; 1.7693x over previous
//
#include <hip/hip_runtime.h>
#include <stdint.h>

#define T_ 1024
#define H_ 256
#define G_ 768

typedef __attribute__((ext_vector_type(8))) short bf16x8;
typedef __attribute__((ext_vector_type(4))) float f32x4;

__device__ __forceinline__ unsigned short f2bf(float f) {
    union { float f; uint32_t u; } v; v.f = f;
    uint32_t u = v.u;
    return (unsigned short)((u + 0x7FFFu + ((u >> 16) & 1u)) >> 16);
}

__device__ __forceinline__ float sigm(float x) {
    x = fminf(fmaxf(x, -30.f), 30.f);
    return 1.f / (1.f + __expf(-x));
}
__device__ __forceinline__ float tanh_f(float x) {
    x = fminf(fmaxf(x, -15.f), 15.f);
    float e = __expf(2.f * x);
    return (e - 1.f) / (e + 1.f);
}

__device__ __forceinline__ void gload_lds16(const void* g, void* l) {
    __builtin_amdgcn_global_load_lds((const __attribute__((address_space(1))) void*)g,
                                     (__attribute__((address_space(3))) void*)l,
                                     16, 0, 0);
}

// Pack W (f32 [layer][768][256]) into per-wave MFMA A-fragment order:
// flat = ((((layer*8 + w)*6 + mt)*8 + kt)*64 + l)*8 + j
// gate = (mt>>1)*256 + w*32 + (mt&1)*16 + (l&15)
// k    = kt*32 + (j&3) + ((l>>4)<<2) + ((j>>2)<<4)
__global__ void pack_weights(const float* __restrict__ W_ih, const float* __restrict__ W_hh,
                             unsigned short* __restrict__ pIH, unsigned short* __restrict__ pHH)
{
    int idx = blockIdx.x * blockDim.x + threadIdx.x;
    if (idx >= 2 * 8 * 6 * 8 * 64 * 8) return;
    int pos = idx;
    int j = pos & 7;  pos >>= 3;
    int l = pos & 63; pos >>= 6;
    int kt = pos & 7; pos >>= 3;
    int mt = pos % 6; pos /= 6;
    int w = pos & 7;  pos >>= 3;
    int layer = pos;
    int gate = (mt >> 1) * 256 + w * 32 + (mt & 1) * 16 + (l & 15);
    int k = kt * 32 + (j & 3) + ((l >> 4) << 2) + ((j >> 2) << 4);
    size_t src = (size_t)layer * G_ * H_ + (size_t)gate * H_ + k;
    pIH[idx] = f2bf(W_ih[src]);
    pHH[idx] = f2bf(W_hh[src]);
}

// xg GEMM: xg^T-tiles = W_ih . seq^T, output in C-fragment layout:
// xg[t][bblk][w][mt][lane][4] f32
// Layer0 src: x f32 [B][T][H] (staged to [k][b] LDS, scalar gather).
// Layer1 src: hseq bf16 fragment layout [bblk][t][kt][lane][8] (staged linear, ds_read_b128).
template<bool SRC_BF16>
__global__ __launch_bounds__(512, 2)
void gemm_xg(const void* __restrict__ srcp, const unsigned short* __restrict__ wpack,
             float* __restrict__ xg, int t0)
{
    extern __shared__ char smem[];
    unsigned short* Bt = (unsigned short*)smem; // [8][4096] shorts = 64KB
    const int tid = threadIdx.x;
    const int w = tid >> 6, l = tid & 63;
    const int bblk = blockIdx.x & 7;
    const int tg = blockIdx.x >> 3;
    const int tbase = t0 + tg * 8;
    const int b = l & 15, g = l >> 4;

    bf16x8 af[6][8];
    {
        const bf16x8* wp = (const bf16x8*)wpack;
        #pragma unroll
        for (int mt = 0; mt < 6; ++mt)
            #pragma unroll
            for (int kt = 0; kt < 8; ++kt)
                af[mt][kt] = wp[((w * 6 + mt) * 8 + kt) * 64 + l];
    }

    if (!SRC_BF16) {
        const float* x = (const float*)srcp;
        const int t_i = w;                 // wave w stages time-slot w
        const int sb = (l >> 2) & 15;      // batch row within block
        const int f0 = (l & 3) * 64;       // feature segment
        const float* row = x + ((size_t)(bblk * 16 + sb) * T_ + (tbase + t_i)) * H_ + f0;
        unsigned short* bt = Bt + t_i * 4096;
        #pragma unroll
        for (int i = 0; i < 64; i += 4) {
            f32x4 v = *(const f32x4*)(row + i);
            int f = f0 + i;
            bt[(f + 0) * 16 + sb] = f2bf(v[0]);
            bt[(f + 1) * 16 + sb] = f2bf(v[1]);
            bt[(f + 2) * 16 + sb] = f2bf(v[2]);
            bt[(f + 3) * 16 + sb] = f2bf(v[3]);
        }
    } else {
        const unsigned short* hs = (const unsigned short*)srcp;
        #pragma unroll
        for (int t_i = 0; t_i < 8; ++t_i) {
            const unsigned short* src = hs + ((size_t)bblk * T_ + (tbase + t_i)) * 4096
                                           + (size_t)(w * 64 + l) * 8;
            gload_lds16(src, Bt + t_i * 4096 + w * 512);
        }
    }
    __syncthreads();

    #pragma unroll 1
    for (int t_i = 0; t_i < 8; ++t_i) {
        const unsigned short* bt = Bt + t_i * 4096;
        f32x4 acc[6];
        #pragma unroll
        for (int mt = 0; mt < 6; ++mt) acc[mt] = (f32x4){0.f, 0.f, 0.f, 0.f};
        #pragma unroll
        for (int kt = 0; kt < 8; ++kt) {
            bf16x8 bf;
            if (SRC_BF16) {
                bf = *(const bf16x8*)(bt + kt * 512 + l * 8);
            } else {
                #pragma unroll
                for (int j = 0; j < 8; ++j) {
                    int k = kt * 32 + (j & 3) + (g << 2) + ((j >> 2) << 4);
                    bf[j] = (short)bt[k * 16 + b];
                }
            }
            #pragma unroll
            for (int mt = 0; mt < 6; ++mt)
                acc[mt] = __builtin_amdgcn_mfma_f32_16x16x32_bf16(af[mt][kt], bf, acc[mt], 0, 0, 0);
        }
        f32x4* dst = (f32x4*)xg + (((size_t)(tg * 8 + t_i) * 8 + bblk) * 8 + w) * 384;
        #pragma unroll
        for (int mt = 0; mt < 6; ++mt)
            dst[mt * 64 + l] = acc[mt];
    }
}

// Persistent recurrence: 8 blocks x 16 batch rows.
// W_hh: 36/48 A-fragments in regs (kt 0..5), 12/48 in LDS (kt 6..7).
// h exchanged via LDS in B-fragment layout (1 ds_write_b128 / 8 ds_read_b128 per step).
// xg consumed via registers, prefetched one step ahead; raw barrier (no vmcnt drain).
template<int LAYER>
__global__ __launch_bounds__(512, 2)
void recur(const float* __restrict__ xg, const unsigned short* __restrict__ wpack,
           const float* __restrict__ bih, const float* __restrict__ bhh,
           unsigned short* __restrict__ hseq, float* __restrict__ hstate,
           float* __restrict__ h2last, int t0, int nsteps, int first)
{
    extern __shared__ char smem[];
    unsigned short* wlds  = (unsigned short*)smem;             // [8 waves][12][64][8] = 96KB
    unsigned short* hfrag = (unsigned short*)(smem + 98304);   // [2][8][64][8] = 16KB
    float* biasl = (float*)(smem + 98304 + 16384);             // [1024] f32 = 4KB
    const int tid = threadIdx.x;
    const int w = tid >> 6, l = tid & 63;
    const int bblk = blockIdx.x;
    const int g = l >> 4;

    // reg-resident A-fragments: kt 0..5
    bf16x8 af[6][6];
    {
        const bf16x8* wp = (const bf16x8*)wpack;
        #pragma unroll
        for (int mt = 0; mt < 6; ++mt)
            #pragma unroll
            for (int kt = 0; kt < 6; ++kt)
                af[mt][kt] = wp[((w * 6 + mt) * 8 + kt) * 64 + l];
    }
    // LDS-resident A-fragments: kt 6,7 (1KB per unit, lane-linear => gload_lds ok)
    #pragma unroll
    for (int mt = 0; mt < 6; ++mt)
        #pragma unroll
        for (int ktm = 0; ktm < 2; ++ktm)
            gload_lds16(wpack + ((((size_t)(w * 6 + mt)) * 8 + 6 + ktm) * 64 + l) * 8,
                        wlds + (w * 12 + mt * 2 + ktm) * 512);

    biasl[tid] = bih[tid] + bhh[tid];          // r,z summed biases (gates 0..511)
    if (tid < 256) {
        biasl[512 + tid] = bih[512 + tid];     // b_ih_n
        biasl[768 + tid] = bhh[512 + tid];     // b_hh_n
    }

    float hreg[2][4];
    if (first) {
        #pragma unroll
        for (int s = 0; s < 2; ++s)
            #pragma unroll
            for (int q = 0; q < 4; ++q) hreg[s][q] = 0.f;
    } else {
        const f32x4* hsv = (const f32x4*)hstate + ((size_t)(bblk * 8 + w) * 64 + l) * 2;
        f32x4 a0 = hsv[0], a1 = hsv[1];
        hreg[0][0] = a0[0]; hreg[0][1] = a0[1]; hreg[0][2] = a0[2]; hreg[0][3] = a0[3];
        hreg[1][0] = a1[0]; hreg[1][1] = a1[1]; hreg[1][2] = a1[2]; hreg[1][3] = a1[3];
    }
    {
        bf16x8 hq;
        #pragma unroll
        for (int s = 0; s < 2; ++s)
            #pragma unroll
            for (int q = 0; q < 4; ++q)
                hq[s * 4 + q] = (short)f2bf(hreg[s][q]);
        *(bf16x8*)(hfrag + w * 512 + l * 8) = hq;   // parity 0
    }
    __syncthreads();   // drains weight gload_lds + hfrag/bias writes (once)

    // xg prologue: registers for it=0
    f32x4 xgr[6];
    {
        const f32x4* xv = (const f32x4*)xg + (((size_t)0 * 8 + bblk) * 8 + w) * 384;
        #pragma unroll
        for (int mt = 0; mt < 6; ++mt) xgr[mt] = xv[mt * 64 + l];
    }

    #pragma unroll 1
    for (int it = 0; it < nsteps; ++it) {
        const int p = it & 1;
        const unsigned short* hb = hfrag + p * 4096;
        bf16x8 hv[8];
        #pragma unroll
        for (int kt = 0; kt < 8; ++kt)
            hv[kt] = *(const bf16x8*)(hb + kt * 512 + l * 8);

        f32x4 acc[6];
        #pragma unroll
        for (int mt = 0; mt < 6; ++mt) acc[mt] = (f32x4){0.f, 0.f, 0.f, 0.f};
        #pragma unroll
        for (int kt = 0; kt < 6; ++kt)
            #pragma unroll
            for (int mt = 0; mt < 6; ++mt)
                acc[mt] = __builtin_amdgcn_mfma_f32_16x16x32_bf16(af[mt][kt], hv[kt], acc[mt], 0, 0, 0);
        #pragma unroll
        for (int ktm = 0; ktm < 2; ++ktm)
            #pragma unroll
            for (int mt = 0; mt < 6; ++mt) {
                bf16x8 a = *(const bf16x8*)(wlds + (w * 12 + mt * 2 + ktm) * 512 + l * 8);
                acc[mt] = __builtin_amdgcn_mfma_f32_16x16x32_bf16(a, hv[6 + ktm], acc[mt], 0, 0, 0);
            }

        // gates (xgr loaded one iter ago; counted vmcnt wait inserted by compiler)
        bf16x8 hq;
        #pragma unroll
        for (int s = 0; s < 2; ++s) {
            f32x4 xr = xgr[0 + s];
            f32x4 xz = xgr[2 + s];
            f32x4 xn = xgr[4 + s];
            #pragma unroll
            for (int q = 0; q < 4; ++q) {
                int go = w * 32 + s * 16 + (g << 2) + q;   // hidden index
                float r = sigm(xr[q] + acc[0 + s][q] + biasl[go]);
                float z = sigm(xz[q] + acc[2 + s][q] + biasl[256 + go]);
                float n = tanh_f(xn[q] + biasl[512 + go] + r * (acc[4 + s][q] + biasl[768 + go]));
                float hn = n + z * (hreg[s][q] - n);
                hreg[s][q] = hn;
                hq[s * 4 + q] = (short)f2bf(hn);
            }
        }
        *(bf16x8*)(hfrag + (p ^ 1) * 4096 + w * 512 + l * 8) = hq;
        if (LAYER == 0)
            *(bf16x8*)(hseq + ((size_t)bblk * T_ + (t0 + it)) * 4096 + (size_t)(w * 64 + l) * 8) = hq;

        // prefetch xg for next step into registers (stays in flight across raw barrier)
        {
            int itn = (it + 1 < nsteps) ? (it + 1) : it;
            const f32x4* xv = (const f32x4*)xg + (((size_t)itn * 8 + bblk) * 8 + w) * 384;
            #pragma unroll
            for (int mt = 0; mt < 6; ++mt) xgr[mt] = xv[mt * 64 + l];
        }
        // raw barrier: drain LDS ops only, leave vmem prefetch in flight
        asm volatile("s_waitcnt lgkmcnt(0)\ns_barrier" ::: "memory");
    }

    f32x4* hsv = (f32x4*)hstate + ((size_t)(bblk * 8 + w) * 64 + l) * 2;
    hsv[0] = (f32x4){hreg[0][0], hreg[0][1], hreg[0][2], hreg[0][3]};
    hsv[1] = (f32x4){hreg[1][0], hreg[1][1], hreg[1][2], hreg[1][3]};
    if (LAYER == 1 && t0 + nsteps == T_) {
        const int b = l & 15;
        #pragma unroll
        for (int s = 0; s < 2; ++s)
            #pragma unroll
            for (int q = 0; q < 4; ++q) {
                int k = w * 32 + s * 16 + (g << 2) + q;
                h2last[(size_t)(bblk * 16 + b) * H_ + k] = hreg[s][q];
            }
    }
}

__global__ void fc_out(const float* __restrict__ h2, const float* __restrict__ W_fc,
                       const float* __restrict__ b_fc, float* __restrict__ out)
{
    __shared__ float hrow[256];
    const int bb = blockIdx.x, i = threadIdx.x;
    hrow[i] = h2[(size_t)bb * 256 + i];
    __syncthreads();
    float acc = b_fc[i];
    const float* wr = W_fc + (size_t)i * 256;
    #pragma unroll 8
    for (int k = 0; k < 256; ++k) acc += hrow[k] * wr[k];
    out[(size_t)bb * 256 + i] = sigm(acc);
}

extern "C" void kernel_launch(void* const* d_in, const int* in_sizes, int n_in,
                              void* d_out, int out_size, void* d_ws, size_t ws_size,
                              hipStream_t stream)
{
    const float* x    = (const float*)d_in[0];
    const float* W_ih = (const float*)d_in[1];
    const float* W_hh = (const float*)d_in[2];
    const float* b_ih = (const float*)d_in[3];
    const float* b_hh = (const float*)d_in[4];
    const float* W_fc = (const float*)d_in[5];
    const float* b_fc = (const float*)d_in[6];
    float* out = (float*)d_out;

    const size_t HSEQ_B = (size_t)8 * T_ * 4096 * 2;   // 64 MB
    const size_t PACK_B = 393216ull * 2;               // 768 KB each
    const size_t HST_B = 131072, H2_B = 131072;
    size_t fixed = HSEQ_B + 2 * PACK_B + HST_B + H2_B;
    int chunk = 1024;
    while (chunk > 64 && fixed + (size_t)chunk * 98304 * 4 > ws_size) chunk >>= 1;

    char* ws = (char*)d_ws;
    float* xg = (float*)ws;
    size_t off = (size_t)chunk * 98304 * 4;
    unsigned short* hseq = (unsigned short*)(ws + off); off += HSEQ_B;
    unsigned short* pIH  = (unsigned short*)(ws + off); off += PACK_B;
    unsigned short* pHH  = (unsigned short*)(ws + off); off += PACK_B;
    float* hstate = (float*)(ws + off); off += HST_B;
    float* h2     = (float*)(ws + off);

    pack_weights<<<1536, 256, 0, stream>>>(W_ih, W_hh, pIH, pHH);

    const int RLDS = 98304 + 16384 + 4096;
    for (int layer = 0; layer < 2; ++layer) {
        const unsigned short* wIH = pIH + (size_t)layer * 196608;
        const unsigned short* wHH = pHH + (size_t)layer * 196608;
        const float* bi = b_ih + layer * G_;
        const float* bh = b_hh + layer * G_;
        for (int c = 0; c * chunk < T_; ++c) {
            int t0 = c * chunk;
            if (layer == 0) {
                gemm_xg<false><<<chunk, 512, 65536, stream>>>(x, wIH, xg, t0);
                recur<0><<<8, 512, RLDS, stream>>>(xg, wHH, bi, bh, hseq, hstate, h2,
                                                   t0, chunk, c == 0);
            } else {
                gemm_xg<true><<<chunk, 512, 65536, stream>>>(hseq, wIH, xg, t0);
                recur<1><<<8, 512, RLDS, stream>>>(xg, wHH, bi, bh, hseq, hstate, h2,
                                                   t0, chunk, c == 0);
            }
        }
    }
    fc_out<<<128, 256, 0, stream>>>(h2, W_fc, b_fc, out);
}

// Round 4
// 4508.142 us; speedup vs baseline: 2.3434x; 1.3245x over previous
//
#include <hip/hip_runtime.h>
#include <stdint.h>

#define T_ 1024
#define H_ 256
#define G_ 768

typedef __attribute__((ext_vector_type(8))) short bf16x8;
typedef __attribute__((ext_vector_type(4))) float f32x4;

__device__ __forceinline__ unsigned short f2bf(float f) {
    union { float f; uint32_t u; } v; v.f = f;
    uint32_t u = v.u;
    return (unsigned short)((u + 0x7FFFu + ((u >> 16) & 1u)) >> 16);
}

// clamp-free, NaN-free activations (inf-safe limits)
__device__ __forceinline__ float sigm(float x) {
    return __builtin_amdgcn_rcpf(1.f + __expf(-x));
}
__device__ __forceinline__ float tanh_f(float x) {
    return __builtin_amdgcn_rcpf(1.f + __expf(-2.f * x)) * 2.f - 1.f;
}

__device__ __forceinline__ unsigned long long pk4bf(float a, float b, float c, float d) {
    uint32_t lo, hi;
    asm("v_cvt_pk_bf16_f32 %0, %1, %2" : "=v"(lo) : "v"(a), "v"(b));
    asm("v_cvt_pk_bf16_f32 %0, %1, %2" : "=v"(hi) : "v"(c), "v"(d));
    return ((unsigned long long)hi << 32) | (unsigned long long)lo;
}

__device__ __forceinline__ void gload_lds16(const void* g, void* l) {
    __builtin_amdgcn_global_load_lds((const __attribute__((address_space(1))) void*)g,
                                     (__attribute__((address_space(3))) void*)l,
                                     16, 0, 0);
}

// Pack W (f32 [layer][768][256]) into MFMA A-fragment order, 48 gate-tiles/layer:
// flat = (((layer*48 + gt)*8 + kt)*64 + l)*8 + j
// gt = half*24 + w*3 + mt  (recur view);  gate = mt*256 + half*128 + w*16 + (l&15)
// k  = kt*32 + (j&3) + ((l>>4)<<2) + ((j>>2)<<4)
__global__ void pack_weights(const float* __restrict__ W_ih, const float* __restrict__ W_hh,
                             unsigned short* __restrict__ pIH, unsigned short* __restrict__ pHH)
{
    int idx = blockIdx.x * blockDim.x + threadIdx.x;
    if (idx >= 2 * 48 * 8 * 64 * 8) return;
    int j = idx & 7;
    int l = (idx >> 3) & 63;
    int kt = (idx >> 9) & 7;
    int gtl = (idx >> 12) % 48;
    int layer = (idx >> 12) / 48;
    int gate = (gtl % 3) * 256 + (gtl / 24) * 128 + ((gtl / 3) % 8) * 16 + (l & 15);
    int k = kt * 32 + (j & 3) + ((l >> 4) << 2) + ((j >> 2) << 4);
    size_t src = (size_t)layer * G_ * H_ + (size_t)gate * H_ + k;
    pIH[idx] = f2bf(W_ih[src]);
    pHH[idx] = f2bf(W_hh[src]);
}

// xg GEMM: output tile gt = w*6+mt at xg[((t*8+bblk)*48 + gt)*64 + l] (f32x4 units).
template<bool SRC_BF16>
__global__ __launch_bounds__(512, 2)
void gemm_xg(const void* __restrict__ srcp, const unsigned short* __restrict__ wpack,
             float* __restrict__ xg, int t0)
{
    extern __shared__ char smem[];
    unsigned short* Bt = (unsigned short*)smem; // [8][4096] shorts = 64KB
    const int tid = threadIdx.x;
    const int w = tid >> 6, l = tid & 63;
    const int bblk = blockIdx.x & 7;
    const int tg = blockIdx.x >> 3;
    const int tbase = t0 + tg * 8;
    const int b = l & 15, g = l >> 4;

    bf16x8 af[6][8];
    {
        const bf16x8* wp = (const bf16x8*)wpack;
        #pragma unroll
        for (int mt = 0; mt < 6; ++mt)
            #pragma unroll
            for (int kt = 0; kt < 8; ++kt)
                af[mt][kt] = wp[((w * 6 + mt) * 8 + kt) * 64 + l];
    }

    if (!SRC_BF16) {
        const float* x = (const float*)srcp;
        const int t_i = w;
        const int sb = (l >> 2) & 15;
        const int f0 = (l & 3) * 64;
        const float* row = x + ((size_t)(bblk * 16 + sb) * T_ + (tbase + t_i)) * H_ + f0;
        unsigned short* bt = Bt + t_i * 4096;
        #pragma unroll
        for (int i = 0; i < 64; i += 4) {
            f32x4 v = *(const f32x4*)(row + i);
            int f = f0 + i;
            bt[(f + 0) * 16 + sb] = f2bf(v[0]);
            bt[(f + 1) * 16 + sb] = f2bf(v[1]);
            bt[(f + 2) * 16 + sb] = f2bf(v[2]);
            bt[(f + 3) * 16 + sb] = f2bf(v[3]);
        }
    } else {
        const unsigned short* hs = (const unsigned short*)srcp;
        #pragma unroll
        for (int t_i = 0; t_i < 8; ++t_i) {
            const unsigned short* src = hs + ((size_t)bblk * T_ + (tbase + t_i)) * 4096
                                           + (size_t)(w * 64 + l) * 8;
            gload_lds16(src, Bt + t_i * 4096 + w * 512);
        }
    }
    __syncthreads();

    #pragma unroll 1
    for (int t_i = 0; t_i < 8; ++t_i) {
        const unsigned short* bt = Bt + t_i * 4096;
        f32x4 acc[6];
        #pragma unroll
        for (int mt = 0; mt < 6; ++mt) acc[mt] = (f32x4){0.f, 0.f, 0.f, 0.f};
        #pragma unroll
        for (int kt = 0; kt < 8; ++kt) {
            bf16x8 bf;
            if (SRC_BF16) {
                bf = *(const bf16x8*)(bt + kt * 512 + l * 8);
            } else {
                #pragma unroll
                for (int j = 0; j < 8; ++j) {
                    int k = kt * 32 + (j & 3) + (g << 2) + ((j >> 2) << 4);
                    bf[j] = (short)bt[k * 16 + b];
                }
            }
            #pragma unroll
            for (int mt = 0; mt < 6; ++mt)
                acc[mt] = __builtin_amdgcn_mfma_f32_16x16x32_bf16(af[mt][kt], bf, acc[mt], 0, 0, 0);
        }
        f32x4* dst = (f32x4*)xg + (((size_t)(tg * 8 + t_i) * 8 + bblk) * 8 + w) * 384;
        #pragma unroll
        for (int mt = 0; mt < 6; ++mt)
            dst[mt * 64 + l] = acc[mt];
    }
}

// Gate-split recurrence: 16 blocks = 8 bblk x 2 halves. Each block: 16 batch rows,
// 384 gates (h[half*128 .. +128)). All W_hh A-fragments in registers (af[3][8]).
// h-half exchange: own half via LDS, partner half via device-scope atomics + flag.
template<int LAYER>
__global__ __launch_bounds__(512, 2)
void recur(const float* __restrict__ xg, const unsigned short* __restrict__ wpack,
           const float* __restrict__ bih, const float* __restrict__ bhh,
           unsigned short* __restrict__ hseq, float* __restrict__ hstate,
           float* __restrict__ h2last, unsigned short* __restrict__ xch,
           int* __restrict__ flags, int t0, int nsteps, int first)
{
    __shared__ unsigned short hfrag[2][4][512];   // 8 KB: [parity][own ktl][lane*8]
    const int tid = threadIdx.x;
    const int w = tid >> 6, l = tid & 63;
    const int bblk = blockIdx.x & 7;
    const int half = blockIdx.x >> 3;
    const int g = l >> 4, b = l & 15;
    const int sbase = LAYER * T_ + t0;
    const int gt = half * 24 + w * 3;

    // A fragments: af[mt][c]; c<4 = own-half kt (half*4+c), c>=4 = partner-half kt
    bf16x8 af[3][8];
    {
        const bf16x8* wp = (const bf16x8*)wpack;
        #pragma unroll
        for (int mt = 0; mt < 3; ++mt)
            #pragma unroll
            for (int c = 0; c < 8; ++c) {
                int ktg = (c < 4) ? (half * 4 + c) : ((1 - half) * 4 + (c - 4));
                af[mt][c] = wp[((size_t)(gt + mt) * 8 + ktg) * 64 + l];
            }
    }

    // biases hoisted to registers (4 hidden units per lane)
    const int hid0 = half * 128 + w * 16 + g * 4;
    float rb[4], zb[4], nbi[4], nbh[4];
    #pragma unroll
    for (int q = 0; q < 4; ++q) {
        rb[q]  = bih[hid0 + q] + bhh[hid0 + q];
        zb[q]  = bih[256 + hid0 + q] + bhh[256 + hid0 + q];
        nbi[q] = bih[512 + hid0 + q];
        nbh[q] = bhh[512 + hid0 + q];
    }

    float hreg[4];
    #pragma unroll
    for (int q = 0; q < 4; ++q)
        hreg[q] = first ? 0.f : hstate[(size_t)(bblk * 16 + b) * H_ + hid0 + q];

    const int ktl_w = w >> 1;          // own-half local kt this wave produces
    const int jo = (w & 1) * 4;        // j-quad within the fragment
    unsigned short* myx = xch + (size_t)(bblk * 2 + half) * 2 * 2048;
    const unsigned short* px = xch + (size_t)(bblk * 2 + (1 - half)) * 2 * 2048;
    int* myflag = flags + (bblk * 2 + half) * 32;
    int* pflag  = flags + (bblk * 2 + (1 - half)) * 32;
    const f32x4* xgv = (const f32x4*)xg;

    // xg prologue for it=0
    f32x4 xgA[3], xgB[3];
    #pragma unroll
    for (int mt = 0; mt < 3; ++mt)
        xgA[mt] = xgv[((size_t)bblk * 48 + gt + mt) * 64 + l];

    auto step = [&](int it, f32x4 (&cur)[3], f32x4 (&nxt)[3]) {
        const int p = it & 1;
        bf16x8 hv[8];
        if (it == 0) {
            // build full-h B fragments from hstate (or zeros)
            #pragma unroll
            for (int c = 0; c < 8; ++c) {
                int ktg = (c < 4) ? (half * 4 + c) : ((1 - half) * 4 + (c - 4));
                #pragma unroll
                for (int j = 0; j < 8; ++j) {
                    int k = ktg * 32 + (j & 3) + (g << 2) + ((j >> 2) << 4);
                    float hvv = first ? 0.f : hstate[(size_t)(bblk * 16 + b) * H_ + k];
                    hv[c][j] = (short)f2bf(hvv);
                }
            }
        } else {
            const int target = sbase + it;
            while (__hip_atomic_load(pflag, __ATOMIC_RELAXED, __HIP_MEMORY_SCOPE_AGENT) < target) {}
            // partner half: 4 fragments via coherence-point loads (issued first)
            #pragma unroll
            for (int c = 0; c < 4; ++c) {
                union { unsigned long long u[2]; bf16x8 v; } uu;
                unsigned long long* ap = (unsigned long long*)(px + (size_t)p * 2048 + c * 512 + l * 8);
                uu.u[0] = __hip_atomic_load(ap, __ATOMIC_RELAXED, __HIP_MEMORY_SCOPE_AGENT);
                uu.u[1] = __hip_atomic_load(ap + 1, __ATOMIC_RELAXED, __HIP_MEMORY_SCOPE_AGENT);
                hv[4 + c] = uu.v;
            }
            // own half from LDS
            #pragma unroll
            for (int c = 0; c < 4; ++c)
                hv[c] = *(const bf16x8*)(&hfrag[p][c][l * 8]);
        }

        f32x4 acc[3];
        #pragma unroll
        for (int mt = 0; mt < 3; ++mt) acc[mt] = (f32x4){0.f, 0.f, 0.f, 0.f};
        #pragma unroll
        for (int c = 0; c < 8; ++c)       // own-half kts (c<4) schedule first
            #pragma unroll
            for (int mt = 0; mt < 3; ++mt)
                acc[mt] = __builtin_amdgcn_mfma_f32_16x16x32_bf16(af[mt][c], hv[c], acc[mt], 0, 0, 0);

        float hn4[4];
        #pragma unroll
        for (int q = 0; q < 4; ++q) {
            float r = sigm(cur[0][q] + acc[0][q] + rb[q]);
            float z = sigm(cur[1][q] + acc[1][q] + zb[q]);
            float n = tanh_f(cur[2][q] + nbi[q] + r * (acc[2][q] + nbh[q]));
            float hn = n + z * (hreg[q] - n);
            hreg[q] = hn;
            hn4[q] = hn;
        }
        unsigned long long packed = pk4bf(hn4[0], hn4[1], hn4[2], hn4[3]);
        *(unsigned long long*)(&hfrag[p ^ 1][ktl_w][l * 8 + jo]) = packed;
        if (it + 1 < nsteps) {
            unsigned long long* sp =
                (unsigned long long*)(myx + (size_t)(p ^ 1) * 2048 + ktl_w * 512 + l * 8 + jo);
            __hip_atomic_store(sp, packed, __ATOMIC_RELAXED, __HIP_MEMORY_SCOPE_AGENT);
        }
        if (LAYER == 0)
            *(unsigned long long*)(hseq + ((size_t)bblk * T_ + (t0 + it)) * 4096
                                   + (size_t)(half * 4 + ktl_w) * 512 + l * 8 + jo) = packed;
        asm volatile("" ::: "memory");  // keep stores older than xg prefetch
        {
            int itn = (it + 1 < nsteps) ? (it + 1) : it;
            #pragma unroll
            for (int mt = 0; mt < 3; ++mt)
                nxt[mt] = xgv[(((size_t)itn * 8 + bblk) * 48 + gt + mt) * 64 + l];
        }
        // drain stores (older) but leave the 3 xg prefetch loads in flight
        asm volatile("s_waitcnt vmcnt(3) lgkmcnt(0)\n\ts_barrier" ::: "memory");
        if (tid == 0 && it + 1 < nsteps)
            __hip_atomic_store(myflag, sbase + it + 1, __ATOMIC_RELAXED, __HIP_MEMORY_SCOPE_AGENT);
    };

    #pragma unroll 1
    for (int it2 = 0; it2 < nsteps; it2 += 2) {
        step(it2,     xgA, xgB);
        step(it2 + 1, xgB, xgA);
    }

    #pragma unroll
    for (int q = 0; q < 4; ++q)
        hstate[(size_t)(bblk * 16 + b) * H_ + hid0 + q] = hreg[q];
    if (LAYER == 1 && t0 + nsteps == T_) {
        #pragma unroll
        for (int q = 0; q < 4; ++q)
            h2last[(size_t)(bblk * 16 + b) * H_ + hid0 + q] = hreg[q];
    }
}

__global__ void fc_out(const float* __restrict__ h2, const float* __restrict__ W_fc,
                       const float* __restrict__ b_fc, float* __restrict__ out)
{
    __shared__ float hrow[256];
    const int bb = blockIdx.x, i = threadIdx.x;
    hrow[i] = h2[(size_t)bb * 256 + i];
    __syncthreads();
    float acc = b_fc[i];
    const float* wr = W_fc + (size_t)i * 256;
    #pragma unroll 8
    for (int k = 0; k < 256; ++k) acc += hrow[k] * wr[k];
    out[(size_t)bb * 256 + i] = sigm(acc);
}

extern "C" void kernel_launch(void* const* d_in, const int* in_sizes, int n_in,
                              void* d_out, int out_size, void* d_ws, size_t ws_size,
                              hipStream_t stream)
{
    const float* x    = (const float*)d_in[0];
    const float* W_ih = (const float*)d_in[1];
    const float* W_hh = (const float*)d_in[2];
    const float* b_ih = (const float*)d_in[3];
    const float* b_hh = (const float*)d_in[4];
    const float* W_fc = (const float*)d_in[5];
    const float* b_fc = (const float*)d_in[6];
    float* out = (float*)d_out;

    const size_t HSEQ_B = (size_t)8 * T_ * 4096 * 2;   // 64 MB
    const size_t PACK_B = 393216ull * 2;               // 768 KB each
    const size_t HST_B = 131072, H2_B = 131072;
    const size_t XCH_B = 131072, FLG_B = 2048;
    size_t fixed = HSEQ_B + 2 * PACK_B + HST_B + H2_B + XCH_B + FLG_B;
    int chunk = 1024;
    while (chunk > 64 && fixed + (size_t)chunk * 393216 > ws_size) chunk >>= 1;

    char* ws = (char*)d_ws;
    float* xg = (float*)ws;
    size_t off = (size_t)chunk * 393216;
    unsigned short* hseq = (unsigned short*)(ws + off); off += HSEQ_B;
    unsigned short* pIH  = (unsigned short*)(ws + off); off += PACK_B;
    unsigned short* pHH  = (unsigned short*)(ws + off); off += PACK_B;
    float* hstate = (float*)(ws + off); off += HST_B;
    float* h2     = (float*)(ws + off); off += H2_B;
    unsigned short* xch = (unsigned short*)(ws + off); off += XCH_B;
    int* flags    = (int*)(ws + off);

    hipMemsetAsync(flags, 0, FLG_B, stream);
    pack_weights<<<1536, 256, 0, stream>>>(W_ih, W_hh, pIH, pHH);

    for (int layer = 0; layer < 2; ++layer) {
        const unsigned short* wIH = pIH + (size_t)layer * 196608;
        const unsigned short* wHH = pHH + (size_t)layer * 196608;
        const float* bi = b_ih + layer * G_;
        const float* bh = b_hh + layer * G_;
        for (int c = 0; c * chunk < T_; ++c) {
            int t0 = c * chunk;
            if (layer == 0) {
                gemm_xg<false><<<chunk, 512, 65536, stream>>>(x, wIH, xg, t0);
                recur<0><<<16, 512, 0, stream>>>(xg, wHH, bi, bh, hseq, hstate, h2,
                                                 xch, flags, t0, chunk, c == 0);
            } else {
                gemm_xg<true><<<chunk, 512, 65536, stream>>>(hseq, wIH, xg, t0);
                recur<1><<<16, 512, 0, stream>>>(xg, wHH, bi, bh, hseq, hstate, h2,
                                                 xch, flags, t0, chunk, c == 0);
            }
        }
    }
    fc_out<<<128, 256, 0, stream>>>(h2, W_fc, b_fc, out);
}

// Round 10
// 3928.022 us; speedup vs baseline: 2.6895x; 1.1477x over previous
//
#include <hip/hip_runtime.h>
#include <stdint.h>

#define T_ 1024
#define H_ 256
#define G_ 768

typedef __attribute__((ext_vector_type(8))) short bf16x8;
typedef __attribute__((ext_vector_type(4))) float f32x4;

__device__ __forceinline__ unsigned short f2bf(float f) {
    union { float f; uint32_t u; } v; v.f = f;
    uint32_t u = v.u;
    return (unsigned short)((u + 0x7FFFu + ((u >> 16) & 1u)) >> 16);
}

// clamp-free, NaN-free activations (inf-safe limits)
__device__ __forceinline__ float sigm(float x) {
    return __builtin_amdgcn_rcpf(1.f + __expf(-x));
}
__device__ __forceinline__ float tanh_f(float x) {
    return __builtin_amdgcn_rcpf(1.f + __expf(-2.f * x)) * 2.f - 1.f;
}

// pack 4 f32 -> 4 bf16 in a u64, scalar-float inputs (K4-proven in recur)
__device__ __forceinline__ unsigned long long pk4bf(float a, float b, float c, float d) {
    uint32_t lo, hi;
    asm("v_cvt_pk_bf16_f32 %0, %1, %2" : "=v"(lo) : "v"(a), "v"(b));
    asm("v_cvt_pk_bf16_f32 %0, %1, %2" : "=v"(hi) : "v"(c), "v"(d));
    return ((unsigned long long)hi << 32) | (unsigned long long)lo;
}

// pack 4 f32 -> u64 with NO inline asm (f2bf bit-twiddle; for gemm epilogue)
__device__ __forceinline__ unsigned long long pk4bf_sw(float a, float b, float c, float d) {
    return (unsigned long long)f2bf(a)
         | ((unsigned long long)f2bf(b) << 16)
         | ((unsigned long long)f2bf(c) << 32)
         | ((unsigned long long)f2bf(d) << 48);
}

// unpack 4 bf16 (bits [15:0],[31:16],[47:32],[63:48]) -> 4 f32, exact
__device__ __forceinline__ void unpk4(unsigned long long v, float* o) {
    uint32_t lo = (uint32_t)v, hi = (uint32_t)(v >> 32);
    union { uint32_t u; float f; } a, b, c, d;
    a.u = lo << 16; b.u = lo & 0xffff0000u;
    c.u = hi << 16; d.u = hi & 0xffff0000u;
    o[0] = a.f; o[1] = b.f; o[2] = c.f; o[3] = d.f;
}

__device__ __forceinline__ void gload_lds16(const void* g, void* l) {
    __builtin_amdgcn_global_load_lds((const __attribute__((address_space(1))) void*)g,
                                     (__attribute__((address_space(3))) void*)l,
                                     16, 0, 0);
}

// Pack W (f32 [layer][768][256]) into per-wave MFMA A-fragment order (K2-proven):
// flat = ((((layer*8 + w)*6 + mt)*8 + kt)*64 + l)*8 + j
// gate = (mt>>1)*256 + w*32 + (mt&1)*16 + (l&15)
// k    = kt*32 + (j&3) + ((l>>4)<<2) + ((j>>2)<<4)
__global__ void pack_weights(const float* __restrict__ W_ih, const float* __restrict__ W_hh,
                             unsigned short* __restrict__ pIH, unsigned short* __restrict__ pHH)
{
    int idx = blockIdx.x * blockDim.x + threadIdx.x;
    if (idx >= 2 * 8 * 6 * 8 * 64 * 8) return;
    int pos = idx;
    int j = pos & 7;  pos >>= 3;
    int l = pos & 63; pos >>= 6;
    int kt = pos & 7; pos >>= 3;
    int mt = pos % 6; pos /= 6;
    int w = pos & 7;  pos >>= 3;
    int layer = pos;
    int gate = (mt >> 1) * 256 + w * 32 + (mt & 1) * 16 + (l & 15);
    int k = kt * 32 + (j & 3) + ((l >> 4) << 2) + ((j >> 2) << 4);
    size_t src = (size_t)layer * G_ * H_ + (size_t)gate * H_ + k;
    pIH[idx] = f2bf(W_ih[src]);
    pHH[idx] = f2bf(W_hh[src]);
}

// xg GEMM: output tile gt = w*6+mt, packed bf16 u64 per lane-tile:
// xg_u64[(tloc*8+bblk)*3072 + w*384 + mt*64 + l]   (tloc = chunk-local t)
// Epilogue packs via f2bf bit-ops ONLY (no inline asm in this kernel).
template<bool SRC_BF16>
__global__ __launch_bounds__(512, 2)
void gemm_xg(const void* __restrict__ srcp, const unsigned short* __restrict__ wpack,
             unsigned long long* __restrict__ xg, int t0)
{
    extern __shared__ char smem[];
    unsigned short* Bt = (unsigned short*)smem; // [8][4096] shorts = 64KB
    const int tid = threadIdx.x;
    const int w = tid >> 6, l = tid & 63;
    const int bblk = blockIdx.x & 7;
    const int tg = blockIdx.x >> 3;
    const int tbase = t0 + tg * 8;
    const int b = l & 15, g = l >> 4;

    bf16x8 af[6][8];
    {
        const bf16x8* wp = (const bf16x8*)wpack;
        #pragma unroll
        for (int mt = 0; mt < 6; ++mt)
            #pragma unroll
            for (int kt = 0; kt < 8; ++kt)
                af[mt][kt] = wp[((w * 6 + mt) * 8 + kt) * 64 + l];
    }

    if (!SRC_BF16) {
        const float* x = (const float*)srcp;
        const int t_i = w;
        const int sb = (l >> 2) & 15;
        const int f0 = (l & 3) * 64;
        const float* row = x + ((size_t)(bblk * 16 + sb) * T_ + (tbase + t_i)) * H_ + f0;
        unsigned short* bt = Bt + t_i * 4096;
        #pragma unroll
        for (int i = 0; i < 64; i += 4) {
            f32x4 v = *(const f32x4*)(row + i);
            int f = f0 + i;
            bt[(f + 0) * 16 + sb] = f2bf(v[0]);
            bt[(f + 1) * 16 + sb] = f2bf(v[1]);
            bt[(f + 2) * 16 + sb] = f2bf(v[2]);
            bt[(f + 3) * 16 + sb] = f2bf(v[3]);
        }
    } else {
        const unsigned short* hs = (const unsigned short*)srcp;
        #pragma unroll
        for (int t_i = 0; t_i < 8; ++t_i) {
            const unsigned short* src = hs + ((size_t)bblk * T_ + (tbase + t_i)) * 4096
                                           + (size_t)(w * 64 + l) * 8;
            gload_lds16(src, Bt + t_i * 4096 + w * 512);
        }
    }
    __syncthreads();

    #pragma unroll 1
    for (int t_i = 0; t_i < 8; ++t_i) {
        const unsigned short* bt = Bt + t_i * 4096;
        f32x4 acc[6];
        #pragma unroll
        for (int mt = 0; mt < 6; ++mt) acc[mt] = (f32x4){0.f, 0.f, 0.f, 0.f};
        #pragma unroll
        for (int kt = 0; kt < 8; ++kt) {
            bf16x8 bf;
            if (SRC_BF16) {
                bf = *(const bf16x8*)(bt + kt * 512 + l * 8);
            } else {
                #pragma unroll
                for (int j = 0; j < 8; ++j) {
                    int k = kt * 32 + (j & 3) + (g << 2) + ((j >> 2) << 4);
                    bf[j] = (short)bt[k * 16 + b];
                }
            }
            #pragma unroll
            for (int mt = 0; mt < 6; ++mt)
                acc[mt] = __builtin_amdgcn_mfma_f32_16x16x32_bf16(af[mt][kt], bf, acc[mt], 0, 0, 0);
        }
        unsigned long long* dst = xg + ((size_t)(tg * 8 + t_i) * 8 + bblk) * 3072 + (size_t)w * 384;
        #pragma unroll
        for (int mt = 0; mt < 6; ++mt)
            dst[mt * 64 + l] = pk4bf_sw(acc[mt][0], acc[mt][1], acc[mt][2], acc[mt][3]);
    }
}

// Zero-communication recurrence (K2 structure + VALU/traffic diet):
// 8 blocks x 16 batch rows; 8 waves exchange full h through LDS hfrag (2 parities,
// one lgkm-only barrier per step). W_hh: kt0..5 in regs (af[6][6]), kt6..7 in LDS.
// xg read per step straight to registers (packed bf16, LLC-resident).
template<int LAYER>
__global__ __launch_bounds__(512, 2)
void recur(const unsigned long long* __restrict__ xg, const unsigned short* __restrict__ wpack,
           const float* __restrict__ bih, const float* __restrict__ bhh,
           unsigned short* __restrict__ hseq, float* __restrict__ hstate,
           float* __restrict__ h2last, int t0, int nsteps, int first)
{
    extern __shared__ char smem[];
    unsigned short* wlds  = (unsigned short*)smem;             // [8][12][512] u16 = 96KB
    unsigned short* hfrag = (unsigned short*)(smem + 98304);   // [2][8][512] u16 = 16KB
    float* biasl = (float*)(smem + 98304 + 16384);             // [1024] f32 = 4KB
    const int tid = threadIdx.x;
    const int w = tid >> 6, l = tid & 63;
    const int bblk = blockIdx.x;
    const int g = l >> 4, b = l & 15;

    // reg-resident A-fragments: kt 0..5
    bf16x8 af[6][6];
    {
        const bf16x8* wp = (const bf16x8*)wpack;
        #pragma unroll
        for (int mt = 0; mt < 6; ++mt)
            #pragma unroll
            for (int kt = 0; kt < 6; ++kt)
                af[mt][kt] = wp[((w * 6 + mt) * 8 + kt) * 64 + l];
    }
    // LDS-resident A-fragments: kt 6,7
    #pragma unroll
    for (int mt = 0; mt < 6; ++mt)
        #pragma unroll
        for (int ktm = 0; ktm < 2; ++ktm)
            gload_lds16(wpack + ((((size_t)(w * 6 + mt)) * 8 + 6 + ktm) * 64 + l) * 8,
                        wlds + (w * 12 + mt * 2 + ktm) * 512);

    biasl[tid] = bih[tid] + bhh[tid];          // r,z summed biases (gates 0..511)
    if (tid < 256) {
        biasl[512 + tid] = bih[512 + tid];     // b_ih_n
        biasl[768 + tid] = bhh[512 + tid];     // b_hh_n
    }

    float hreg[2][4];
    #pragma unroll
    for (int s = 0; s < 2; ++s)
        #pragma unroll
        for (int q = 0; q < 4; ++q) {
            int hid = w * 32 + s * 16 + g * 4 + q;
            hreg[s][q] = first ? 0.f : hstate[(size_t)(bblk * 16 + b) * H_ + hid];
        }
    // init hfrag parity 0: wave w owns kt=w; two u64 quads (s=0, s=1)
    {
        unsigned long long p0 = pk4bf(hreg[0][0], hreg[0][1], hreg[0][2], hreg[0][3]);
        unsigned long long p1 = pk4bf(hreg[1][0], hreg[1][1], hreg[1][2], hreg[1][3]);
        *(unsigned long long*)(&hfrag[(size_t)w * 512 + l * 8])     = p0;
        *(unsigned long long*)(&hfrag[(size_t)w * 512 + l * 8 + 4]) = p1;
    }
    __syncthreads();   // drains weight gload_lds + hfrag/bias writes (once)

    #pragma unroll 1
    for (int it = 0; it < nsteps; ++it) {
        const int pr = it & 1;
        // 1) xg for THIS step -> registers (LLC-resident; latency hidden by MFMAs)
        unsigned long long xgc[6];
        {
            const unsigned long long* xv = xg + ((size_t)it * 8 + bblk) * 3072 + (size_t)w * 384;
            #pragma unroll
            for (int mt = 0; mt < 6; ++mt) xgc[mt] = xv[mt * 64 + l];
        }
        // 2) h fragments + MFMAs
        const unsigned short* hb = hfrag + (size_t)pr * 4096;
        f32x4 acc[6];
        #pragma unroll
        for (int mt = 0; mt < 6; ++mt) acc[mt] = (f32x4){0.f, 0.f, 0.f, 0.f};
        {
            bf16x8 hv[4];
            #pragma unroll
            for (int kt = 0; kt < 4; ++kt)
                hv[kt] = *(const bf16x8*)(hb + kt * 512 + l * 8);
            #pragma unroll
            for (int kt = 0; kt < 4; ++kt)
                #pragma unroll
                for (int mt = 0; mt < 6; ++mt)
                    acc[mt] = __builtin_amdgcn_mfma_f32_16x16x32_bf16(af[mt][kt], hv[kt], acc[mt], 0, 0, 0);
        }
        {
            bf16x8 hv[4];
            #pragma unroll
            for (int kt = 0; kt < 4; ++kt)
                hv[kt] = *(const bf16x8*)(hb + (4 + kt) * 512 + l * 8);
            #pragma unroll
            for (int kt = 0; kt < 2; ++kt)
                #pragma unroll
                for (int mt = 0; mt < 6; ++mt)
                    acc[mt] = __builtin_amdgcn_mfma_f32_16x16x32_bf16(af[mt][4 + kt], hv[kt], acc[mt], 0, 0, 0);
            #pragma unroll
            for (int ktm = 0; ktm < 2; ++ktm)
                #pragma unroll
                for (int mt = 0; mt < 6; ++mt) {
                    bf16x8 a = *(const bf16x8*)(wlds + (w * 12 + mt * 2 + ktm) * 512 + l * 8);
                    acc[mt] = __builtin_amdgcn_mfma_f32_16x16x32_bf16(a, hv[2 + ktm], acc[mt], 0, 0, 0);
                }
        }
        // 3) gates
        unsigned long long pks[2];
        #pragma unroll
        for (int s = 0; s < 2; ++s) {
            float cx0[4], cx1[4], cx2[4];
            unpk4(xgc[0 + s], cx0);
            unpk4(xgc[2 + s], cx1);
            unpk4(xgc[4 + s], cx2);
            float hn4[4];
            #pragma unroll
            for (int q = 0; q < 4; ++q) {
                int hid = w * 32 + s * 16 + g * 4 + q;
                float r = sigm(cx0[q] + acc[0 + s][q] + biasl[hid]);
                float z = sigm(cx1[q] + acc[2 + s][q] + biasl[256 + hid]);
                float n = tanh_f(cx2[q] + biasl[512 + hid] + r * (acc[4 + s][q] + biasl[768 + hid]));
                float hn = n + z * (hreg[s][q] - n);
                hreg[s][q] = hn;
                hn4[q] = hn;
            }
            pks[s] = pk4bf(hn4[0], hn4[1], hn4[2], hn4[3]);
        }
        // 4) publish h: LDS (next parity) + hseq (LAYER 0)
        *(unsigned long long*)(&hfrag[(size_t)(pr ^ 1) * 4096 + w * 512 + l * 8])     = pks[0];
        *(unsigned long long*)(&hfrag[(size_t)(pr ^ 1) * 4096 + w * 512 + l * 8 + 4]) = pks[1];
        if (LAYER == 0) {
            unsigned long long* dv = (unsigned long long*)(hseq
                + ((size_t)bblk * T_ + (t0 + it)) * 4096 + (size_t)w * 512 + l * 8);
            dv[0] = pks[0];
            dv[1] = pks[1];
        }
        // 5) lgkm-only barrier: hfrag ordered; hseq stores drain at dispatch end
        asm volatile("s_waitcnt lgkmcnt(0)\n\ts_barrier" ::: "memory");
    }

    #pragma unroll
    for (int s = 0; s < 2; ++s)
        #pragma unroll
        for (int q = 0; q < 4; ++q) {
            int hid = w * 32 + s * 16 + g * 4 + q;
            hstate[(size_t)(bblk * 16 + b) * H_ + hid] = hreg[s][q];
        }
    if (LAYER == 1 && t0 + nsteps == T_) {
        #pragma unroll
        for (int s = 0; s < 2; ++s)
            #pragma unroll
            for (int q = 0; q < 4; ++q) {
                int hid = w * 32 + s * 16 + g * 4 + q;
                h2last[(size_t)(bblk * 16 + b) * H_ + hid] = hreg[s][q];
            }
    }
}

__global__ void fc_out(const float* __restrict__ h2, const float* __restrict__ W_fc,
                       const float* __restrict__ b_fc, float* __restrict__ out)
{
    __shared__ float hrow[256];
    const int bb = blockIdx.x, i = threadIdx.x;
    hrow[i] = h2[(size_t)bb * 256 + i];
    __syncthreads();
    float acc = b_fc[i];
    const float* wr = W_fc + (size_t)i * 256;
    #pragma unroll 8
    for (int k = 0; k < 256; ++k) acc += hrow[k] * wr[k];
    out[(size_t)bb * 256 + i] = sigm(acc);
}

extern "C" void kernel_launch(void* const* d_in, const int* in_sizes, int n_in,
                              void* d_out, int out_size, void* d_ws, size_t ws_size,
                              hipStream_t stream)
{
    const float* x    = (const float*)d_in[0];
    const float* W_ih = (const float*)d_in[1];
    const float* W_hh = (const float*)d_in[2];
    const float* b_ih = (const float*)d_in[3];
    const float* b_hh = (const float*)d_in[4];
    const float* W_fc = (const float*)d_in[5];
    const float* b_fc = (const float*)d_in[6];
    float* out = (float*)d_out;

    const size_t HSEQ_B = (size_t)8 * T_ * 4096 * 2;   // 64 MB
    const size_t PACK_B = 393216ull * 2;               // 768 KB each
    const size_t HST_B = 131072, H2_B = 131072;
    size_t fixed = HSEQ_B + 2 * PACK_B + HST_B + H2_B;
    // xg: per chunk-t, 8 bblk x 3072 u64 x 8 B = 196608 BYTES
    int chunk = 1024;
    while (chunk > 64 && fixed + (size_t)chunk * 196608 > ws_size) chunk >>= 1;

    char* ws = (char*)d_ws;
    unsigned long long* xg = (unsigned long long*)ws;  // chunk * 24576 u64
    size_t off = (size_t)chunk * 196608;
    unsigned short* hseq = (unsigned short*)(ws + off); off += HSEQ_B;
    unsigned short* pIH  = (unsigned short*)(ws + off); off += PACK_B;
    unsigned short* pHH  = (unsigned short*)(ws + off); off += PACK_B;
    float* hstate = (float*)(ws + off); off += HST_B;
    float* h2     = (float*)(ws + off);

    pack_weights<<<1536, 256, 0, stream>>>(W_ih, W_hh, pIH, pHH);

    const int RLDS = 98304 + 16384 + 4096;
    for (int layer = 0; layer < 2; ++layer) {
        const unsigned short* wIH = pIH + (size_t)layer * 196608;
        const unsigned short* wHH = pHH + (size_t)layer * 196608;
        const float* bi = b_ih + layer * G_;
        const float* bh = b_hh + layer * G_;
        for (int c = 0; c * chunk < T_; ++c) {
            int t0 = c * chunk;
            if (layer == 0) {
                gemm_xg<false><<<chunk, 512, 65536, stream>>>(x, wIH, xg, t0);
                recur<0><<<8, 512, RLDS, stream>>>(xg, wHH, bi, bh, hseq, hstate, h2,
                                                   t0, chunk, c == 0);
            } else {
                gemm_xg<true><<<chunk, 512, 65536, stream>>>(hseq, wIH, xg, t0);
                recur<1><<<8, 512, RLDS, stream>>>(xg, wHH, bi, bh, hseq, hstate, h2,
                                                   t0, chunk, c == 0);
            }
        }
    }
    fc_out<<<128, 256, 0, stream>>>(h2, W_fc, b_fc, out);
}

// Round 11
// 3415.746 us; speedup vs baseline: 3.0928x; 1.1500x over previous
//
#include <hip/hip_runtime.h>
#include <stdint.h>

#define T_ 1024
#define H_ 256
#define G_ 768

typedef __attribute__((ext_vector_type(8))) short bf16x8;
typedef __attribute__((ext_vector_type(4))) float f32x4;

__device__ __forceinline__ unsigned short f2bf(float f) {
    union { float f; uint32_t u; } v; v.f = f;
    uint32_t u = v.u;
    return (unsigned short)((u + 0x7FFFu + ((u >> 16) & 1u)) >> 16);
}

// clamp-free, NaN-free activations (inf-safe limits)
__device__ __forceinline__ float sigm(float x) {
    return __builtin_amdgcn_rcpf(1.f + __expf(-x));
}
__device__ __forceinline__ float tanh_f(float x) {
    return __builtin_amdgcn_rcpf(1.f + __expf(-2.f * x)) * 2.f - 1.f;
}

// pack 4 f32 -> 4 bf16 in a u64, scalar-float inputs (K4/K10-proven in recur ONLY;
// condemned on MFMA acc values in gemm — see K5..K9 post-mortems)
__device__ __forceinline__ unsigned long long pk4bf(float a, float b, float c, float d) {
    uint32_t lo, hi;
    asm("v_cvt_pk_bf16_f32 %0, %1, %2" : "=v"(lo) : "v"(a), "v"(b));
    asm("v_cvt_pk_bf16_f32 %0, %1, %2" : "=v"(hi) : "v"(c), "v"(d));
    return ((unsigned long long)hi << 32) | (unsigned long long)lo;
}

// pack 4 f32 -> u64 with NO inline asm (f2bf bit-twiddle; for gemm epilogue)
__device__ __forceinline__ unsigned long long pk4bf_sw(float a, float b, float c, float d) {
    return (unsigned long long)f2bf(a)
         | ((unsigned long long)f2bf(b) << 16)
         | ((unsigned long long)f2bf(c) << 32)
         | ((unsigned long long)f2bf(d) << 48);
}

// unpack 4 bf16 (bits [15:0],[31:16],[47:32],[63:48]) -> 4 f32, exact
__device__ __forceinline__ void unpk4(unsigned long long v, float* o) {
    uint32_t lo = (uint32_t)v, hi = (uint32_t)(v >> 32);
    union { uint32_t u; float f; } a, b, c, d;
    a.u = lo << 16; b.u = lo & 0xffff0000u;
    c.u = hi << 16; d.u = hi & 0xffff0000u;
    o[0] = a.f; o[1] = b.f; o[2] = c.f; o[3] = d.f;
}

__device__ __forceinline__ void gload_lds16(const void* g, void* l) {
    __builtin_amdgcn_global_load_lds((const __attribute__((address_space(1))) void*)g,
                                     (__attribute__((address_space(3))) void*)l,
                                     16, 0, 0);
}

// Pack W (f32 [layer][768][256]) into per-wave MFMA A-fragment order (K2-proven):
// flat = ((((layer*8 + w)*6 + mt)*8 + kt)*64 + l)*8 + j
// gate = (mt>>1)*256 + w*32 + (mt&1)*16 + (l&15)
// k    = kt*32 + (j&3) + ((l>>4)<<2) + ((j>>2)<<4)
__global__ void pack_weights(const float* __restrict__ W_ih, const float* __restrict__ W_hh,
                             unsigned short* __restrict__ pIH, unsigned short* __restrict__ pHH)
{
    int idx = blockIdx.x * blockDim.x + threadIdx.x;
    if (idx >= 2 * 8 * 6 * 8 * 64 * 8) return;
    int pos = idx;
    int j = pos & 7;  pos >>= 3;
    int l = pos & 63; pos >>= 6;
    int kt = pos & 7; pos >>= 3;
    int mt = pos % 6; pos /= 6;
    int w = pos & 7;  pos >>= 3;
    int layer = pos;
    int gate = (mt >> 1) * 256 + w * 32 + (mt & 1) * 16 + (l & 15);
    int k = kt * 32 + (j & 3) + ((l >> 4) << 2) + ((j >> 2) << 4);
    size_t src = (size_t)layer * G_ * H_ + (size_t)gate * H_ + k;
    pIH[idx] = f2bf(W_ih[src]);
    pHH[idx] = f2bf(W_hh[src]);
}

// xg GEMM with bias fold: for gates<512 add (b_ih+b_hh), for n-gates add b_ih,
// BEFORE bf16 packing. Output packed bf16 u64 per lane-tile:
// xg_u64[(tloc*8+bblk)*3072 + w*384 + mt*64 + l]
template<bool SRC_BF16>
__global__ __launch_bounds__(512, 2)
void gemm_xg(const void* __restrict__ srcp, const unsigned short* __restrict__ wpack,
             const float* __restrict__ bih, const float* __restrict__ bhh,
             unsigned long long* __restrict__ xg, int t0)
{
    extern __shared__ char smem[];
    unsigned short* Bt = (unsigned short*)smem; // [8][4096] shorts = 64KB
    const int tid = threadIdx.x;
    const int w = tid >> 6, l = tid & 63;
    const int bblk = blockIdx.x & 7;
    const int tg = blockIdx.x >> 3;
    const int tbase = t0 + tg * 8;
    const int b = l & 15, g = l >> 4;

    bf16x8 af[6][8];
    {
        const bf16x8* wp = (const bf16x8*)wpack;
        #pragma unroll
        for (int mt = 0; mt < 6; ++mt)
            #pragma unroll
            for (int kt = 0; kt < 8; ++kt)
                af[mt][kt] = wp[((w * 6 + mt) * 8 + kt) * 64 + l];
    }

    // folded biases for this wave's 6 tiles: C row = g*4+q
    float bsum[6][4];
    #pragma unroll
    for (int mt = 0; mt < 6; ++mt)
        #pragma unroll
        for (int q = 0; q < 4; ++q) {
            int gate = (mt >> 1) * 256 + w * 32 + (mt & 1) * 16 + g * 4 + q;
            bsum[mt][q] = (gate < 512) ? (bih[gate] + bhh[gate]) : bih[gate];
        }

    if (!SRC_BF16) {
        const float* x = (const float*)srcp;
        const int t_i = w;
        const int sb = (l >> 2) & 15;
        const int f0 = (l & 3) * 64;
        const float* row = x + ((size_t)(bblk * 16 + sb) * T_ + (tbase + t_i)) * H_ + f0;
        unsigned short* bt = Bt + t_i * 4096;
        #pragma unroll
        for (int i = 0; i < 64; i += 4) {
            f32x4 v = *(const f32x4*)(row + i);
            int f = f0 + i;
            bt[(f + 0) * 16 + sb] = f2bf(v[0]);
            bt[(f + 1) * 16 + sb] = f2bf(v[1]);
            bt[(f + 2) * 16 + sb] = f2bf(v[2]);
            bt[(f + 3) * 16 + sb] = f2bf(v[3]);
        }
    } else {
        const unsigned short* hs = (const unsigned short*)srcp;
        #pragma unroll
        for (int t_i = 0; t_i < 8; ++t_i) {
            const unsigned short* src = hs + ((size_t)bblk * T_ + (tbase + t_i)) * 4096
                                           + (size_t)(w * 64 + l) * 8;
            gload_lds16(src, Bt + t_i * 4096 + w * 512);
        }
    }
    __syncthreads();

    #pragma unroll 1
    for (int t_i = 0; t_i < 8; ++t_i) {
        const unsigned short* bt = Bt + t_i * 4096;
        f32x4 acc[6];
        #pragma unroll
        for (int mt = 0; mt < 6; ++mt) acc[mt] = (f32x4){0.f, 0.f, 0.f, 0.f};
        #pragma unroll
        for (int kt = 0; kt < 8; ++kt) {
            bf16x8 bf;
            if (SRC_BF16) {
                bf = *(const bf16x8*)(bt + kt * 512 + l * 8);
            } else {
                #pragma unroll
                for (int j = 0; j < 8; ++j) {
                    int k = kt * 32 + (j & 3) + (g << 2) + ((j >> 2) << 4);
                    bf[j] = (short)bt[k * 16 + b];
                }
            }
            #pragma unroll
            for (int mt = 0; mt < 6; ++mt)
                acc[mt] = __builtin_amdgcn_mfma_f32_16x16x32_bf16(af[mt][kt], bf, acc[mt], 0, 0, 0);
        }
        unsigned long long* dst = xg + ((size_t)(tg * 8 + t_i) * 8 + bblk) * 3072 + (size_t)w * 384;
        #pragma unroll
        for (int mt = 0; mt < 6; ++mt)
            dst[mt * 64 + l] = pk4bf_sw(acc[mt][0] + bsum[mt][0], acc[mt][1] + bsum[mt][1],
                                        acc[mt][2] + bsum[mt][2], acc[mt][3] + bsum[mt][3]);
    }
}

// Zero-communication recurrence, LDS diet:
// 8 blocks x 16 batch rows; 8 waves exchange full h through LDS hfrag.
// W_hh: kt0..6 in regs (af[6][7] = 168 VGPR), only kt7 in LDS (6 b128/step).
// Biases folded into xg at gemm; only bhh_n kept (8 regs). No biasl array.
template<int LAYER>
__global__ __launch_bounds__(512, 2)
void recur(const unsigned long long* __restrict__ xg, const unsigned short* __restrict__ wpack,
           const float* __restrict__ bhh,
           unsigned short* __restrict__ hseq, float* __restrict__ hstate,
           float* __restrict__ h2last, int t0, int nsteps, int first)
{
    extern __shared__ char smem[];
    unsigned short* wlds  = (unsigned short*)smem;             // [8][6][512] u16 = 48KB
    unsigned short* hfrag = (unsigned short*)(smem + 49152);   // [2][8][512] u16 = 16KB
    const int tid = threadIdx.x;
    const int w = tid >> 6, l = tid & 63;
    const int bblk = blockIdx.x;
    const int g = l >> 4, b = l & 15;

    // reg-resident A-fragments: kt 0..6
    bf16x8 af[6][7];
    {
        const bf16x8* wp = (const bf16x8*)wpack;
        #pragma unroll
        for (int mt = 0; mt < 6; ++mt)
            #pragma unroll
            for (int kt = 0; kt < 7; ++kt)
                af[mt][kt] = wp[((w * 6 + mt) * 8 + kt) * 64 + l];
    }
    // LDS-resident A-fragments: kt 7 only
    #pragma unroll
    for (int mt = 0; mt < 6; ++mt)
        gload_lds16(wpack + ((((size_t)(w * 6 + mt)) * 8 + 7) * 64 + l) * 8,
                    wlds + (w * 6 + mt) * 512);

    // n-gate hidden bias in registers (the only bias recur needs)
    float nbh[2][4];
    #pragma unroll
    for (int s = 0; s < 2; ++s)
        #pragma unroll
        for (int q = 0; q < 4; ++q)
            nbh[s][q] = bhh[512 + w * 32 + s * 16 + g * 4 + q];

    float hreg[2][4];
    #pragma unroll
    for (int s = 0; s < 2; ++s)
        #pragma unroll
        for (int q = 0; q < 4; ++q) {
            int hid = w * 32 + s * 16 + g * 4 + q;
            hreg[s][q] = first ? 0.f : hstate[(size_t)(bblk * 16 + b) * H_ + hid];
        }
    // init hfrag parity 0: wave w owns kt=w; two u64 quads (s=0, s=1)
    {
        unsigned long long p0 = pk4bf(hreg[0][0], hreg[0][1], hreg[0][2], hreg[0][3]);
        unsigned long long p1 = pk4bf(hreg[1][0], hreg[1][1], hreg[1][2], hreg[1][3]);
        *(unsigned long long*)(&hfrag[(size_t)w * 512 + l * 8])     = p0;
        *(unsigned long long*)(&hfrag[(size_t)w * 512 + l * 8 + 4]) = p1;
    }
    __syncthreads();   // drains weight gload_lds + hfrag writes (once)

    #pragma unroll 1
    for (int it = 0; it < nsteps; ++it) {
        const int pr = it & 1;
        // 1) xg for THIS step -> registers (issued first, consumed after MFMAs)
        unsigned long long xgc[6];
        {
            const unsigned long long* xv = xg + ((size_t)it * 8 + bblk) * 3072 + (size_t)w * 384;
            #pragma unroll
            for (int mt = 0; mt < 6; ++mt) xgc[mt] = xv[mt * 64 + l];
        }
        // 2) h fragments (paired reads) + MFMAs
        const unsigned short* hb = hfrag + (size_t)pr * 4096;
        f32x4 acc[6];
        #pragma unroll
        for (int mt = 0; mt < 6; ++mt) acc[mt] = (f32x4){0.f, 0.f, 0.f, 0.f};
        #pragma unroll
        for (int kp = 0; kp < 3; ++kp) {
            bf16x8 h0 = *(const bf16x8*)(hb + (2 * kp) * 512 + l * 8);
            bf16x8 h1 = *(const bf16x8*)(hb + (2 * kp + 1) * 512 + l * 8);
            #pragma unroll
            for (int mt = 0; mt < 6; ++mt)
                acc[mt] = __builtin_amdgcn_mfma_f32_16x16x32_bf16(af[mt][2 * kp], h0, acc[mt], 0, 0, 0);
            #pragma unroll
            for (int mt = 0; mt < 6; ++mt)
                acc[mt] = __builtin_amdgcn_mfma_f32_16x16x32_bf16(af[mt][2 * kp + 1], h1, acc[mt], 0, 0, 0);
        }
        {
            bf16x8 h0 = *(const bf16x8*)(hb + 6 * 512 + l * 8);
            bf16x8 h1 = *(const bf16x8*)(hb + 7 * 512 + l * 8);
            #pragma unroll
            for (int mt = 0; mt < 6; ++mt)
                acc[mt] = __builtin_amdgcn_mfma_f32_16x16x32_bf16(af[mt][6], h0, acc[mt], 0, 0, 0);
            #pragma unroll
            for (int mt = 0; mt < 6; ++mt) {
                bf16x8 a = *(const bf16x8*)(wlds + (w * 6 + mt) * 512 + l * 8);
                acc[mt] = __builtin_amdgcn_mfma_f32_16x16x32_bf16(a, h1, acc[mt], 0, 0, 0);
            }
        }
        // 3) gates (all biases except bhh_n pre-folded into xg)
        unsigned long long pks[2];
        #pragma unroll
        for (int s = 0; s < 2; ++s) {
            float cx0[4], cx1[4], cx2[4];
            unpk4(xgc[0 + s], cx0);
            unpk4(xgc[2 + s], cx1);
            unpk4(xgc[4 + s], cx2);
            float hn4[4];
            #pragma unroll
            for (int q = 0; q < 4; ++q) {
                float r = sigm(cx0[q] + acc[0 + s][q]);
                float z = sigm(cx1[q] + acc[2 + s][q]);
                float n = tanh_f(cx2[q] + r * (acc[4 + s][q] + nbh[s][q]));
                float hn = n + z * (hreg[s][q] - n);
                hreg[s][q] = hn;
                hn4[q] = hn;
            }
            pks[s] = pk4bf(hn4[0], hn4[1], hn4[2], hn4[3]);
        }
        // 4) publish h: LDS (next parity) + hseq (LAYER 0)
        *(unsigned long long*)(&hfrag[(size_t)(pr ^ 1) * 4096 + w * 512 + l * 8])     = pks[0];
        *(unsigned long long*)(&hfrag[(size_t)(pr ^ 1) * 4096 + w * 512 + l * 8 + 4]) = pks[1];
        if (LAYER == 0) {
            unsigned long long* dv = (unsigned long long*)(hseq
                + ((size_t)bblk * T_ + (t0 + it)) * 4096 + (size_t)w * 512 + l * 8);
            dv[0] = pks[0];
            dv[1] = pks[1];
        }
        // 5) lgkm-only barrier: hfrag ordered; hseq stores drain at dispatch end
        asm volatile("s_waitcnt lgkmcnt(0)\n\ts_barrier" ::: "memory");
    }

    #pragma unroll
    for (int s = 0; s < 2; ++s)
        #pragma unroll
        for (int q = 0; q < 4; ++q) {
            int hid = w * 32 + s * 16 + g * 4 + q;
            hstate[(size_t)(bblk * 16 + b) * H_ + hid] = hreg[s][q];
        }
    if (LAYER == 1 && t0 + nsteps == T_) {
        #pragma unroll
        for (int s = 0; s < 2; ++s)
            #pragma unroll
            for (int q = 0; q < 4; ++q) {
                int hid = w * 32 + s * 16 + g * 4 + q;
                h2last[(size_t)(bblk * 16 + b) * H_ + hid] = hreg[s][q];
            }
    }
}

__global__ void fc_out(const float* __restrict__ h2, const float* __restrict__ W_fc,
                       const float* __restrict__ b_fc, float* __restrict__ out)
{
    __shared__ float hrow[256];
    const int bb = blockIdx.x, i = threadIdx.x;
    hrow[i] = h2[(size_t)bb * 256 + i];
    __syncthreads();
    float acc = b_fc[i];
    const float* wr = W_fc + (size_t)i * 256;
    #pragma unroll 8
    for (int k = 0; k < 256; ++k) acc += hrow[k] * wr[k];
    out[(size_t)bb * 256 + i] = sigm(acc);
}

extern "C" void kernel_launch(void* const* d_in, const int* in_sizes, int n_in,
                              void* d_out, int out_size, void* d_ws, size_t ws_size,
                              hipStream_t stream)
{
    const float* x    = (const float*)d_in[0];
    const float* W_ih = (const float*)d_in[1];
    const float* W_hh = (const float*)d_in[2];
    const float* b_ih = (const float*)d_in[3];
    const float* b_hh = (const float*)d_in[4];
    const float* W_fc = (const float*)d_in[5];
    const float* b_fc = (const float*)d_in[6];
    float* out = (float*)d_out;

    const size_t HSEQ_B = (size_t)8 * T_ * 4096 * 2;   // 64 MB
    const size_t PACK_B = 393216ull * 2;               // 768 KB each
    const size_t HST_B = 131072, H2_B = 131072;
    size_t fixed = HSEQ_B + 2 * PACK_B + HST_B + H2_B;
    // xg: per chunk-t, 8 bblk x 3072 u64 x 8 B = 196608 BYTES
    int chunk = 1024;
    while (chunk > 64 && fixed + (size_t)chunk * 196608 > ws_size) chunk >>= 1;

    char* ws = (char*)d_ws;
    unsigned long long* xg = (unsigned long long*)ws;  // chunk * 24576 u64
    size_t off = (size_t)chunk * 196608;
    unsigned short* hseq = (unsigned short*)(ws + off); off += HSEQ_B;
    unsigned short* pIH  = (unsigned short*)(ws + off); off += PACK_B;
    unsigned short* pHH  = (unsigned short*)(ws + off); off += PACK_B;
    float* hstate = (float*)(ws + off); off += HST_B;
    float* h2     = (float*)(ws + off);

    pack_weights<<<1536, 256, 0, stream>>>(W_ih, W_hh, pIH, pHH);

    const int RLDS = 49152 + 16384;   // wlds(kt7) + hfrag
    for (int layer = 0; layer < 2; ++layer) {
        const unsigned short* wIH = pIH + (size_t)layer * 196608;
        const unsigned short* wHH = pHH + (size_t)layer * 196608;
        const float* bi = b_ih + layer * G_;
        const float* bh = b_hh + layer * G_;
        for (int c = 0; c * chunk < T_; ++c) {
            int t0 = c * chunk;
            if (layer == 0) {
                gemm_xg<false><<<chunk, 512, 65536, stream>>>(x, wIH, bi, bh, xg, t0);
                recur<0><<<8, 512, RLDS, stream>>>(xg, wHH, bh, hseq, hstate, h2,
                                                   t0, chunk, c == 0);
            } else {
                gemm_xg<true><<<chunk, 512, 65536, stream>>>(hseq, wIH, bi, bh, xg, t0);
                recur<1><<<8, 512, RLDS, stream>>>(xg, wHH, bh, hseq, hstate, h2,
                                                   t0, chunk, c == 0);
            }
        }
    }
    fc_out<<<128, 256, 0, stream>>>(h2, W_fc, b_fc, out);
}